// Round 7
// baseline (231.511 us; speedup 1.0000x reference)
//
#include <hip/hip_runtime.h>
#include <math.h>

#define NB 8
#define NL 1024
#define ND 512
#define NT 2047         // L + S - 1
#define TOPK 20         // int(3 * log(1024))
#define LMOD 2096128    // 2047 * 1024

typedef __attribute__((ext_vector_type(8))) short short8;
typedef __attribute__((ext_vector_type(4))) float f32x4;

static __device__ __forceinline__ unsigned short bf16_rne(float x) {
    unsigned int u = __builtin_bit_cast(unsigned int, x);
    unsigned int r = (u + 0x7fffu + ((u >> 16) & 1u)) >> 16;
    return (unsigned short)r;
}
static __device__ __forceinline__ float bf16_to_f(unsigned short h) {
    unsigned int u = ((unsigned int)h) << 16;
    return __builtin_bit_cast(float, u);
}

// ---------------------------------------------------------------------------
// Kernel T: transpose + split-bf16 convert; also zeroes S (replaces memset
// node — S is only consumed by k_gemm, after this kernel completes).
// q[b][l][d] f32 -> Thi/Tlo[(which*NB+b)][d][l] bf16 (hi = rne(x), lo = rne(x-hi))
// ---------------------------------------------------------------------------
__global__ __launch_bounds__(256) void k_tr(const float* __restrict__ q,
                                            const float* __restrict__ kk,
                                            unsigned short* __restrict__ Thi,
                                            unsigned short* __restrict__ Tlo,
                                            float* __restrict__ S) {
    __shared__ float tile[64][65];
    const int which = blockIdx.z;          // 0=q, 1=k
    const int b  = blockIdx.y;
    const int l0 = (blockIdx.x & 15) * 64;
    const int d0 = (blockIdx.x >> 4) * 64;
    const int t = threadIdx.x;
    if (which == 0 && blockIdx.x == 0) {   // 8 blocks zero S[b][*]
        for (int i = t; i < 1023; i += 256) S[b * 1023 + i] = 0.f;
    }
    const float* src = (which ? kk : q) + (size_t)b * NL * ND;
    const int r = t >> 4, c = t & 15;
    #pragma unroll
    for (int rr = 0; rr < 4; ++rr) {
        const float4 v = *(const float4*)&src[(size_t)(l0 + r + 16 * rr) * ND + d0 + c * 4];
        tile[r + 16 * rr][c * 4 + 0] = v.x;
        tile[r + 16 * rr][c * 4 + 1] = v.y;
        tile[r + 16 * rr][c * 4 + 2] = v.z;
        tile[r + 16 * rr][c * 4 + 3] = v.w;
    }
    __syncthreads();
    unsigned short* hi = Thi + ((size_t)which * NB + b) * (size_t)ND * NL;
    unsigned short* lo = Tlo + ((size_t)which * NB + b) * (size_t)ND * NL;
    #pragma unroll
    for (int p = 0; p < 2; ++p) {
        const int c2 = t + 256 * p;        // 0..511
        const int dl = c2 >> 3;            // 0..63
        const int l8 = (c2 & 7) * 8;
        short8 vh, vl;
        #pragma unroll
        for (int i = 0; i < 8; ++i) {
            const float x = tile[l8 + i][dl];
            const unsigned short h = bf16_rne(x);
            vh[i] = (short)h;
            vl[i] = (short)bf16_rne(x - bf16_to_f(h));
        }
        *(short8*)&hi[(size_t)(d0 + dl) * NL + l0 + l8] = vh;
        *(short8*)&lo[(size_t)(d0 + dl) * NL + l0 + l8] = vl;
    }
}

// ---------------------------------------------------------------------------
// Kernel G: MFMA Gram GEMM.  G = qhi·khi^T + qhi·klo^T + qlo·khi^T.
// r6 -> r7: GBK 64->32, KSPLIT 4->8 (1024 blocks), LDS 77->45 KB ->
// 3 blocks/CU (launch_bounds 256,3) for deeper latency hiding.  Register
// prefetch of next K-step; batch-affinity (b = id&7) keeps each batch's 4 MB
// of planes + S atomics in one XCD's L2; per-wave sd slices; GPAD=8 keeps
// fragment ds_read_b128 at worst 2-way bank aliasing (free).
// ---------------------------------------------------------------------------
#define GBK 32
#define GPAD 8
#define GKT 4            // K-steps per block (K = 128 per block)

__global__ __launch_bounds__(256, 3) void k_gemm(const unsigned short* __restrict__ Thi,
                                                 const unsigned short* __restrict__ Tlo,
                                                 float* __restrict__ S) {
    __shared__ unsigned short Ahi[128][GBK + GPAD];
    __shared__ unsigned short Alo[128][GBK + GPAD];
    __shared__ unsigned short Bhi[128][GBK + GPAD];
    __shared__ unsigned short Blo[128][GBK + GPAD];
    __shared__ float sd4[4][256];
    const int id   = blockIdx.x;
    const int b    = id & 7;                   // XCD affinity by batch
    const int rest = id >> 3;                  // 0..127
    const int mt = rest & 3, nt = (rest >> 2) & 3, kq = rest >> 4;  // kq 0..7
    const int tid  = threadIdx.x;
    const int lane = tid & 63, w = tid >> 6;
    const int wr = w >> 1, wc = w & 1;         // wave -> 64x64 sub-tile
    const int m = lane & 15, g = lane >> 4;    // frag row/col + k-group

    const size_t plane = (size_t)ND * NL;
    const unsigned short* qhi = Thi + (size_t)b * plane;
    const unsigned short* khi = Thi + ((size_t)NB + b) * plane;
    const unsigned short* qlo = Tlo + (size_t)b * plane;
    const unsigned short* klo = Tlo + ((size_t)NB + b) * plane;

    f32x4 acc[4][4];
    #pragma unroll
    for (int i = 0; i < 4; ++i)
        #pragma unroll
        for (int j = 0; j < 4; ++j) acc[i][j] = (f32x4)(0.f);

    const int kbase = kq * GKT;
    short8 r_ah[2], r_al[2], r_bh[2], r_bl[2];
    #pragma unroll
    for (int p = 0; p < 2; ++p) {
        const int cc  = tid + 256 * p;         // 0..511
        const int row = cc >> 2, col8 = (cc & 3) * 8;
        const size_t ga = (size_t)(mt * 128 + row) * NL + kbase * GBK + col8;
        const size_t gb = (size_t)(nt * 128 + row) * NL + kbase * GBK + col8;
        r_ah[p] = *(const short8*)&qhi[ga];
        r_al[p] = *(const short8*)&qlo[ga];
        r_bh[p] = *(const short8*)&khi[gb];
        r_bl[p] = *(const short8*)&klo[gb];
    }

    for (int kt = 0; kt < GKT; ++kt) {
        __syncthreads();
        #pragma unroll
        for (int p = 0; p < 2; ++p) {
            const int cc  = tid + 256 * p;
            const int row = cc >> 2, col8 = (cc & 3) * 8;
            *(short8*)&Ahi[row][col8] = r_ah[p];
            *(short8*)&Alo[row][col8] = r_al[p];
            *(short8*)&Bhi[row][col8] = r_bh[p];
            *(short8*)&Blo[row][col8] = r_bl[p];
        }
        __syncthreads();
        if (kt + 1 < GKT) {                    // prefetch next K-step; lands
            #pragma unroll                     // during the MFMA phase below
            for (int p = 0; p < 2; ++p) {
                const int cc  = tid + 256 * p;
                const int row = cc >> 2, col8 = (cc & 3) * 8;
                const size_t ga = (size_t)(mt * 128 + row) * NL + (kbase + kt + 1) * GBK + col8;
                const size_t gb = (size_t)(nt * 128 + row) * NL + (kbase + kt + 1) * GBK + col8;
                r_ah[p] = *(const short8*)&qhi[ga];
                r_al[p] = *(const short8*)&qlo[ga];
                r_bh[p] = *(const short8*)&khi[gb];
                r_bl[p] = *(const short8*)&klo[gb];
            }
        }
        short8 ah[4], al[4], bh[4], bl[4];
        #pragma unroll
        for (int i = 0; i < 4; ++i) {
            ah[i] = *(const short8*)&Ahi[wr * 64 + i * 16 + m][g * 8];
            al[i] = *(const short8*)&Alo[wr * 64 + i * 16 + m][g * 8];
        }
        #pragma unroll
        for (int j = 0; j < 4; ++j) {
            bh[j] = *(const short8*)&Bhi[wc * 64 + j * 16 + m][g * 8];
            bl[j] = *(const short8*)&Blo[wc * 64 + j * 16 + m][g * 8];
        }
        #pragma unroll
        for (int i = 0; i < 4; ++i)
            #pragma unroll
            for (int j = 0; j < 4; ++j) {
                acc[i][j] = __builtin_amdgcn_mfma_f32_16x16x32_bf16(ah[i], bh[j], acc[i][j], 0, 0, 0);
                acc[i][j] = __builtin_amdgcn_mfma_f32_16x16x32_bf16(ah[i], bl[j], acc[i][j], 0, 0, 0);
                acc[i][j] = __builtin_amdgcn_mfma_f32_16x16x32_bf16(al[i], bh[j], acc[i][j], 0, 0, 0);
            }
    }

    // --- epilogue: diagonal sums. delta = row - col (global: + (mt-nt)*128) ---
    for (int i = tid; i < 1024; i += 256) ((float*)sd4)[i] = 0.f;
    __syncthreads();
    float bin[7][4];
    #pragma unroll
    for (int u = 0; u < 7; ++u)
        #pragma unroll
        for (int r2 = 0; r2 < 4; ++r2) bin[u][r2] = 0.f;
    #pragma unroll
    for (int i = 0; i < 4; ++i)
        #pragma unroll
        for (int j = 0; j < 4; ++j)
            #pragma unroll
            for (int r2 = 0; r2 < 4; ++r2) bin[i - j + 3][r2] += acc[i][j][r2];
    const int basei = (wr - wc) * 64 + g * 4 - m + 127;
    #pragma unroll
    for (int u = 0; u < 7; ++u)
        #pragma unroll
        for (int r2 = 0; r2 < 4; ++r2)
            atomicAdd(&sd4[w][basei + (u - 3) * 16 + r2], bin[u][r2]);
    __syncthreads();
    const int doff = (mt - nt) * 128 + 511 - 127;
    if (tid < 255) {
        const float vsum = sd4[0][tid] + sd4[1][tid] + sd4[2][tid] + sd4[3][tid];
        atomicAdd(&S[b * 1023 + doff + tid], vsum);
    }
}

// ---------------------------------------------------------------------------
// Kernel M: fused spectrum->mean via the Dirichlet closed form:
//   mean[b,t] = (1/(2047*1024)) * sum_j S[b][j] * sin(1025*pi*u)/sin(pi*u),
//   u = (1024*t - (j-511)*2047)/L mod 1, L = 2047*1024.
// Argument reduction in EXACT integer arithmetic, symmetric-mapped to
// [-L/2, L/2] so the denominator arg is dense near 0 (no cancellation at the
// singularity). One wave per (b,t), 16 j-terms/lane, butterfly reduce.
// Replaces the k_pdft + k_mean pair (one node, no pbar intermediate).
// ---------------------------------------------------------------------------
__global__ __launch_bounds__(256) void k_mean2(const float* __restrict__ S,
                                               float* __restrict__ mv) {
    __shared__ float sh[1023];
    const int b = blockIdx.y;
    for (int i = threadIdx.x; i < 1023; i += 256) sh[i] = S[b * 1023 + i];
    __syncthreads();
    const int wave = threadIdx.x >> 6, lane = threadIdx.x & 63;
    const int t = blockIdx.x * 4 + wave;   // 0..2047
    if (t >= NT) return;
    const float invL = 1.0f / (float)LMOD;
    float acc = 0.f;
    #pragma unroll
    for (int i = 0; i < 16; ++i) {
        const int j = lane + 64 * i;
        if (j < 1023) {
            int un = t * 1024 + (511 - j) * 2047;      // [-1.05M, 3.15M]
            un %= LMOD; if (un < 0) un += LMOD;        // exact u_num in [0,L)
            float D;
            if (un == 0) {
                D = 1025.f;                            // only (t=0, j=511)
            } else {
                const int un2 = (un > LMOD / 2) ? un - LMOD : un;     // [-L/2,L/2]
                long long yy = ((long long)un * 1025LL) % (2LL * LMOD);
                if (yy >= LMOD) yy -= 2LL * LMOD;                     // [-L, L)
                const float num = sinpif((float)yy * invL);
                const float den = fabsf(sinpif((float)un2 * invL));   // sin(pi*u)>0
                D = num / den;
            }
            acc = fmaf(sh[j], D, acc);
        }
    }
    #pragma unroll
    for (int off = 32; off; off >>= 1) acc += __shfl_xor(acc, off);
    if (lane == 0)
        mv[(size_t)b * NT + t] = acc * (1.0f / (2047.0f * 1024.0f));
}

// ---------------------------------------------------------------------------
// Kernel C: per-batch exact top-20 (ties -> lower index), softmax; batch 0's
// indices -> shifts. 256 threads: 8-iter scans + wave/LDS reduce.
// ---------------------------------------------------------------------------
__global__ __launch_bounds__(256) void k_topk(const float* __restrict__ mv,
                                              float* __restrict__ wts,
                                              int* __restrict__ shifts) {
    __shared__ float v[NT];
    __shared__ float topv[TOPK];
    __shared__ int   topi[TOPK];
    __shared__ float wv[4];
    __shared__ int   wi[4];
    const int b = blockIdx.x;
    const int t = threadIdx.x;
    const int lane = t & 63, wave = t >> 6;
    for (int i = t; i < NT; i += 256) v[i] = mv[(size_t)b * NT + i];
    __syncthreads();
    for (int kkk = 0; kkk < TOPK; ++kkk) {
        float bv = -INFINITY; int bi = 0x7fffffff;
        #pragma unroll
        for (int s = 0; s < 8; ++s) {
            const int i = t + 256 * s;
            if (i < NT) {
                const float x = v[i];
                if (x > bv) { bv = x; bi = i; }
            }
        }
        #pragma unroll
        for (int off = 32; off; off >>= 1) {
            const float ov = __shfl_down(bv, off);
            const int   oi = __shfl_down(bi, off);
            if (ov > bv || (ov == bv && oi < bi)) { bv = ov; bi = oi; }
        }
        if (lane == 0) { wv[wave] = bv; wi[wave] = bi; }
        __syncthreads();
        if (t == 0) {
            bv = wv[0]; bi = wi[0];
            #pragma unroll
            for (int ww = 1; ww < 4; ++ww)
                if (wv[ww] > bv || (wv[ww] == bv && wi[ww] < bi)) { bv = wv[ww]; bi = wi[ww]; }
            topv[kkk] = bv; topi[kkk] = bi;
            v[bi] = -INFINITY;
        }
        __syncthreads();
    }
    if (t == 0) {
        float m = topv[0], sum = 0.f, e[TOPK];
        #pragma unroll
        for (int i = 0; i < TOPK; ++i) { e[i] = expf(topv[i] - m); sum += e[i]; }
        #pragma unroll
        for (int i = 0; i < TOPK; ++i) wts[b * TOPK + i] = e[i] / sum;
        if (b == 0) {
            #pragma unroll
            for (int i = 0; i < TOPK; ++i) shifts[i] = topi[i];
        }
    }
}

// ---------------------------------------------------------------------------
// Kernel D: out[b,l,:] = Σ_k w[b,k] * values[b, (l+shift_k) & 1023, :]
// b = blockIdx.x & 7: XCD affinity so values[b] (2.1 MB) stays L2-resident.
// ---------------------------------------------------------------------------
__global__ __launch_bounds__(128) void k_out(const float* __restrict__ vals,
                                             const float* __restrict__ wts,
                                             const int* __restrict__ shifts,
                                             float* __restrict__ out) {
    __shared__ float w[TOPK];
    __shared__ int   sh[TOPK];
    const int id = blockIdx.x;
    const int b = id & 7;                // XCD affinity
    const int l = id >> 3;
    const int t = threadIdx.x;
    if (t < TOPK) { w[t] = wts[b * TOPK + t]; sh[t] = shifts[t]; }
    __syncthreads();
    float4 acc = make_float4(0.f, 0.f, 0.f, 0.f);
    const float4* vb = (const float4*)(vals + (size_t)b * NL * ND);
    #pragma unroll 4
    for (int kkk = 0; kkk < TOPK; ++kkk) {
        const int sl = (l + sh[kkk]) & (NL - 1);
        const float4 x = vb[(size_t)sl * (ND / 4) + t];
        const float wk = w[kkk];
        acc.x = fmaf(wk, x.x, acc.x);
        acc.y = fmaf(wk, x.y, acc.y);
        acc.z = fmaf(wk, x.z, acc.z);
        acc.w = fmaf(wk, x.w, acc.w);
    }
    ((float4*)out)[((size_t)b * NL + l) * (ND / 4) + t] = acc;
}

extern "C" void kernel_launch(void* const* d_in, const int* in_sizes, int n_in,
                              void* d_out, int out_size, void* d_ws, size_t ws_size,
                              hipStream_t stream) {
    const float* q = (const float*)d_in[0];
    const float* k = (const float*)d_in[1];
    const float* v = (const float*)d_in[2];
    float* out    = (float*)d_out;

    const size_t plane = (size_t)ND * NL;                 // 512*1024
    unsigned short* Thi = (unsigned short*)d_ws;          // 2*NB planes bf16
    unsigned short* Tlo = Thi + 2 * NB * plane;           // 2*NB planes bf16
    float* S      = (float*)(Tlo + 2 * NB * plane);       // NB * 1023
    float* mv     = S + NB * 1023;                        // NB * NT
    float* wts    = mv + NB * NT;                         // NB * TOPK
    int*   shifts = (int*)(wts + NB * TOPK);              // TOPK ints

    k_tr   <<<dim3(128, NB, 2), 256, 0, stream>>>(q, k, Thi, Tlo, S);
    k_gemm <<<1024, 256, 0, stream>>>(Thi, Tlo, S);
    k_mean2<<<dim3(512, NB), 256, 0, stream>>>(S, mv);
    k_topk <<<NB, 256, 0, stream>>>(mv, wts, shifts);
    k_out  <<<NL * NB, 128, 0, stream>>>(v, wts, shifts, out);
}

// Round 9
// 202.694 us; speedup vs baseline: 1.1422x; 1.1422x over previous
//
#include <hip/hip_runtime.h>
#include <math.h>

#define NB 8
#define NL 1024
#define ND 512
#define NF 513          // rfft bins of length-1024 transform
#define NT 2047         // L + S - 1
#define TOPK 20         // int(3 * log(1024))

typedef __attribute__((ext_vector_type(8))) short short8;
typedef __attribute__((ext_vector_type(4))) float f32x4;

static __device__ __forceinline__ unsigned short bf16_rne(float x) {
    unsigned int u = __builtin_bit_cast(unsigned int, x);
    unsigned int r = (u + 0x7fffu + ((u >> 16) & 1u)) >> 16;
    return (unsigned short)r;
}
static __device__ __forceinline__ float bf16_to_f(unsigned short h) {
    unsigned int u = ((unsigned int)h) << 16;
    return __builtin_bit_cast(float, u);
}

// ---------------------------------------------------------------------------
// Kernel T: transpose + split-bf16 convert; also zeroes S (replaces memset).
// q[b][l][d] f32 -> Thi/Tlo[(which*NB+b)][d][l] bf16 (hi = rne(x), lo = rne(x-hi))
// ---------------------------------------------------------------------------
__global__ __launch_bounds__(256) void k_tr(const float* __restrict__ q,
                                            const float* __restrict__ kk,
                                            unsigned short* __restrict__ Thi,
                                            unsigned short* __restrict__ Tlo,
                                            float* __restrict__ S) {
    __shared__ float tile[64][65];
    const int which = blockIdx.z;          // 0=q, 1=k
    const int b  = blockIdx.y;
    const int l0 = (blockIdx.x & 15) * 64;
    const int d0 = (blockIdx.x >> 4) * 64;
    const int t = threadIdx.x;
    if (which == 0 && blockIdx.x == 0) {   // 8 blocks zero S[b][*]
        for (int i = t; i < 1023; i += 256) S[b * 1023 + i] = 0.f;
    }
    const float* src = (which ? kk : q) + (size_t)b * NL * ND;
    const int r = t >> 4, c = t & 15;
    #pragma unroll
    for (int rr = 0; rr < 4; ++rr) {
        const float4 v = *(const float4*)&src[(size_t)(l0 + r + 16 * rr) * ND + d0 + c * 4];
        tile[r + 16 * rr][c * 4 + 0] = v.x;
        tile[r + 16 * rr][c * 4 + 1] = v.y;
        tile[r + 16 * rr][c * 4 + 2] = v.z;
        tile[r + 16 * rr][c * 4 + 3] = v.w;
    }
    __syncthreads();
    unsigned short* hi = Thi + ((size_t)which * NB + b) * (size_t)ND * NL;
    unsigned short* lo = Tlo + ((size_t)which * NB + b) * (size_t)ND * NL;
    #pragma unroll
    for (int p = 0; p < 2; ++p) {
        const int c2 = t + 256 * p;        // 0..511
        const int dl = c2 >> 3;            // 0..63
        const int l8 = (c2 & 7) * 8;
        short8 vh, vl;
        #pragma unroll
        for (int i = 0; i < 8; ++i) {
            const float x = tile[l8 + i][dl];
            const unsigned short h = bf16_rne(x);
            vh[i] = (short)h;
            vl[i] = (short)bf16_rne(x - bf16_to_f(h));
        }
        *(short8*)&hi[(size_t)(d0 + dl) * NL + l0 + l8] = vh;
        *(short8*)&lo[(size_t)(d0 + dl) * NL + l0 + l8] = vl;
    }
}

// ---------------------------------------------------------------------------
// Kernel G: MFMA Gram GEMM.  G = qhi·khi^T + qhi·klo^T + qlo·khi^T.
// GBK=32, KSPLIT=8 (1024 blocks), LDS 45 KB -> 3 blocks/CU; register prefetch
// of next K-step; batch-affinity (b = id&7) pins each batch's planes +
// S-atomics to one XCD's L2; per-wave sd slices; GPAD=8 -> <=2-way LDS alias.
// ---------------------------------------------------------------------------
#define GBK 32
#define GPAD 8
#define GKT 4            // K-steps per block (K = 128 per block)

__global__ __launch_bounds__(256, 3) void k_gemm(const unsigned short* __restrict__ Thi,
                                                 const unsigned short* __restrict__ Tlo,
                                                 float* __restrict__ S) {
    __shared__ unsigned short Ahi[128][GBK + GPAD];
    __shared__ unsigned short Alo[128][GBK + GPAD];
    __shared__ unsigned short Bhi[128][GBK + GPAD];
    __shared__ unsigned short Blo[128][GBK + GPAD];
    __shared__ float sd4[4][256];
    const int id   = blockIdx.x;
    const int b    = id & 7;                   // XCD affinity by batch
    const int rest = id >> 3;                  // 0..127
    const int mt = rest & 3, nt = (rest >> 2) & 3, kq = rest >> 4;  // kq 0..7
    const int tid  = threadIdx.x;
    const int lane = tid & 63, w = tid >> 6;
    const int wr = w >> 1, wc = w & 1;         // wave -> 64x64 sub-tile
    const int m = lane & 15, g = lane >> 4;    // frag row/col + k-group

    const size_t plane = (size_t)ND * NL;
    const unsigned short* qhi = Thi + (size_t)b * plane;
    const unsigned short* khi = Thi + ((size_t)NB + b) * plane;
    const unsigned short* qlo = Tlo + (size_t)b * plane;
    const unsigned short* klo = Tlo + ((size_t)NB + b) * plane;

    f32x4 acc[4][4];
    #pragma unroll
    for (int i = 0; i < 4; ++i)
        #pragma unroll
        for (int j = 0; j < 4; ++j) acc[i][j] = (f32x4)(0.f);

    const int kbase = kq * GKT;
    short8 r_ah[2], r_al[2], r_bh[2], r_bl[2];
    #pragma unroll
    for (int p = 0; p < 2; ++p) {
        const int cc  = tid + 256 * p;         // 0..511
        const int row = cc >> 2, col8 = (cc & 3) * 8;
        const size_t ga = (size_t)(mt * 128 + row) * NL + kbase * GBK + col8;
        const size_t gb = (size_t)(nt * 128 + row) * NL + kbase * GBK + col8;
        r_ah[p] = *(const short8*)&qhi[ga];
        r_al[p] = *(const short8*)&qlo[ga];
        r_bh[p] = *(const short8*)&khi[gb];
        r_bl[p] = *(const short8*)&klo[gb];
    }

    for (int kt = 0; kt < GKT; ++kt) {
        __syncthreads();
        #pragma unroll
        for (int p = 0; p < 2; ++p) {
            const int cc  = tid + 256 * p;
            const int row = cc >> 2, col8 = (cc & 3) * 8;
            *(short8*)&Ahi[row][col8] = r_ah[p];
            *(short8*)&Alo[row][col8] = r_al[p];
            *(short8*)&Bhi[row][col8] = r_bh[p];
            *(short8*)&Blo[row][col8] = r_bl[p];
        }
        __syncthreads();
        if (kt + 1 < GKT) {                    // prefetch next K-step; lands
            #pragma unroll                     // during the MFMA phase below
            for (int p = 0; p < 2; ++p) {
                const int cc  = tid + 256 * p;
                const int row = cc >> 2, col8 = (cc & 3) * 8;
                const size_t ga = (size_t)(mt * 128 + row) * NL + (kbase + kt + 1) * GBK + col8;
                const size_t gb = (size_t)(nt * 128 + row) * NL + (kbase + kt + 1) * GBK + col8;
                r_ah[p] = *(const short8*)&qhi[ga];
                r_al[p] = *(const short8*)&qlo[ga];
                r_bh[p] = *(const short8*)&khi[gb];
                r_bl[p] = *(const short8*)&klo[gb];
            }
        }
        short8 ah[4], al[4], bh[4], bl[4];
        #pragma unroll
        for (int i = 0; i < 4; ++i) {
            ah[i] = *(const short8*)&Ahi[wr * 64 + i * 16 + m][g * 8];
            al[i] = *(const short8*)&Alo[wr * 64 + i * 16 + m][g * 8];
        }
        #pragma unroll
        for (int j = 0; j < 4; ++j) {
            bh[j] = *(const short8*)&Bhi[wc * 64 + j * 16 + m][g * 8];
            bl[j] = *(const short8*)&Blo[wc * 64 + j * 16 + m][g * 8];
        }
        #pragma unroll
        for (int i = 0; i < 4; ++i)
            #pragma unroll
            for (int j = 0; j < 4; ++j) {
                acc[i][j] = __builtin_amdgcn_mfma_f32_16x16x32_bf16(ah[i], bh[j], acc[i][j], 0, 0, 0);
                acc[i][j] = __builtin_amdgcn_mfma_f32_16x16x32_bf16(ah[i], bl[j], acc[i][j], 0, 0, 0);
                acc[i][j] = __builtin_amdgcn_mfma_f32_16x16x32_bf16(al[i], bh[j], acc[i][j], 0, 0, 0);
            }
    }

    // --- epilogue: diagonal sums. delta = row - col (global: + (mt-nt)*128) ---
    for (int i = tid; i < 1024; i += 256) ((float*)sd4)[i] = 0.f;
    __syncthreads();
    float bin[7][4];
    #pragma unroll
    for (int u = 0; u < 7; ++u)
        #pragma unroll
        for (int r2 = 0; r2 < 4; ++r2) bin[u][r2] = 0.f;
    #pragma unroll
    for (int i = 0; i < 4; ++i)
        #pragma unroll
        for (int j = 0; j < 4; ++j)
            #pragma unroll
            for (int r2 = 0; r2 < 4; ++r2) bin[i - j + 3][r2] += acc[i][j][r2];
    const int basei = (wr - wc) * 64 + g * 4 - m + 127;
    #pragma unroll
    for (int u = 0; u < 7; ++u)
        #pragma unroll
        for (int r2 = 0; r2 < 4; ++r2)
            atomicAdd(&sd4[w][basei + (u - 3) * 16 + r2], bin[u][r2]);
    __syncthreads();
    const int doff = (mt - nt) * 128 + 511 - 127;
    if (tid < 255) {
        const float vsum = sd4[0][tid] + sd4[1][tid] + sd4[2][tid] + sd4[3][tid];
        atomicAdd(&S[b * 1023 + doff + tid], vsum);
    }
}

// ---------------------------------------------------------------------------
// Kernel P: P̄[b][f] = sum_j S[b][j] e^{-2πi f (j-511)/1024}.
// One wave per (b,f): lanes split j, exact sincosf per term, butterfly reduce.
// (r7's fused Dirichlet form was 56 µs of trans-pipe work — two-stage DFT is
// ~2.5x fewer transcendental ops; reverted.)
// ---------------------------------------------------------------------------
__global__ __launch_bounds__(64) void k_pdft(const float* __restrict__ S,
                                             float* __restrict__ pbar) {
    const int b = blockIdx.y;
    const int f = blockIdx.x;              // 0..512
    const int lane = threadIdx.x;
    const float w = 2.0f * 3.14159265358979323846f / 1024.0f;
    float re = 0.f, im = 0.f;
    #pragma unroll
    for (int i = 0; i < 16; ++i) {
        const int j = lane + 64 * i;
        if (j < 1023) {
            const int mm = (f * (j - 511)) & 1023;   // exact mod (pow2, two's compl.)
            float s, c;
            sincosf(w * (float)mm, &s, &c);
            const float x = S[b * 1023 + j];
            re = fmaf(x, c, re);
            im = fmaf(x, -s, im);
        }
    }
    #pragma unroll
    for (int off = 32; off; off >>= 1) {
        re += __shfl_xor(re, off);
        im += __shfl_xor(im, off);
    }
    if (lane == 0) {
        pbar[b * 2 * NF + 2 * f]     = re;
        pbar[b * 2 * NF + 2 * f + 1] = im;
    }
}

// ---------------------------------------------------------------------------
// Kernel B: mean_value[b,t] = (1/(2047*1024)) * (P̄[0] + 2Σ_{f=1..512}
//            (P̄re[f] cos(2πft/2047) - P̄im[f] sin(2πft/2047)))
// One wave per (b,t), 4 waves/block; lanes split f, butterfly reduce.
// ---------------------------------------------------------------------------
__global__ __launch_bounds__(256) void k_mean(const float* __restrict__ pbar,
                                              float* __restrict__ mv) {
    __shared__ float P[2 * NF];
    const int b = blockIdx.y;
    for (int i = threadIdx.x; i < 2 * NF; i += 256)
        P[i] = pbar[(size_t)b * (2 * NF) + i];
    __syncthreads();
    const int wave = threadIdx.x >> 6, lane = threadIdx.x & 63;
    const int t = blockIdx.x * 4 + wave;   // 0..2047
    if (t >= NT) return;
    const float w2 = 2.0f * 3.14159265358979323846f / 2047.0f;
    float acc = 0.f;
    #pragma unroll
    for (int i = 0; i < 8; ++i) {
        const int f = 1 + lane + 64 * i;   // covers 1..512 exactly
        const int mm = (f * t) % 2047;
        float s, c;
        sincosf(w2 * (float)mm, &s, &c);
        acc = fmaf(P[2 * f], c, acc);
        acc = fmaf(-P[2 * f + 1], s, acc);
    }
    acc *= 2.0f;
    #pragma unroll
    for (int off = 32; off; off >>= 1) acc += __shfl_xor(acc, off);
    if (lane == 0)
        mv[(size_t)b * NT + t] = (acc + P[0]) * (1.0f / (2047.0f * 1024.0f));
}

// ---------------------------------------------------------------------------
// Kernel C: per-batch exact top-20 (ties -> lower index), softmax; batch 0's
// indices -> shifts. 256 threads: 8-iter scans + wave/LDS reduce.
// ---------------------------------------------------------------------------
__global__ __launch_bounds__(256) void k_topk(const float* __restrict__ mv,
                                              float* __restrict__ wts,
                                              int* __restrict__ shifts) {
    __shared__ float v[NT];
    __shared__ float topv[TOPK];
    __shared__ int   topi[TOPK];
    __shared__ float wv[4];
    __shared__ int   wi[4];
    const int b = blockIdx.x;
    const int t = threadIdx.x;
    const int lane = t & 63, wave = t >> 6;
    for (int i = t; i < NT; i += 256) v[i] = mv[(size_t)b * NT + i];
    __syncthreads();
    for (int kkk = 0; kkk < TOPK; ++kkk) {
        float bv = -INFINITY; int bi = 0x7fffffff;
        #pragma unroll
        for (int s = 0; s < 8; ++s) {
            const int i = t + 256 * s;
            if (i < NT) {
                const float x = v[i];
                if (x > bv) { bv = x; bi = i; }
            }
        }
        #pragma unroll
        for (int off = 32; off; off >>= 1) {
            const float ov = __shfl_down(bv, off);
            const int   oi = __shfl_down(bi, off);
            if (ov > bv || (ov == bv && oi < bi)) { bv = ov; bi = oi; }
        }
        if (lane == 0) { wv[wave] = bv; wi[wave] = bi; }
        __syncthreads();
        if (t == 0) {
            bv = wv[0]; bi = wi[0];
            #pragma unroll
            for (int ww = 1; ww < 4; ++ww)
                if (wv[ww] > bv || (wv[ww] == bv && wi[ww] < bi)) { bv = wv[ww]; bi = wi[ww]; }
            topv[kkk] = bv; topi[kkk] = bi;
            v[bi] = -INFINITY;
        }
        __syncthreads();
    }
    if (t == 0) {
        float m = topv[0], sum = 0.f, e[TOPK];
        #pragma unroll
        for (int i = 0; i < TOPK; ++i) { e[i] = expf(topv[i] - m); sum += e[i]; }
        #pragma unroll
        for (int i = 0; i < TOPK; ++i) wts[b * TOPK + i] = e[i] / sum;
        if (b == 0) {
            #pragma unroll
            for (int i = 0; i < TOPK; ++i) shifts[i] = topi[i];
        }
    }
}

// ---------------------------------------------------------------------------
// Kernel D: out[b,l,:] = Σ_k w[b,k] * values[b, (l+shift_k) & 1023, :]
// b = blockIdx.x & 7: XCD affinity so values[b] (2.1 MB) stays L2-resident.
// ---------------------------------------------------------------------------
__global__ __launch_bounds__(128) void k_out(const float* __restrict__ vals,
                                             const float* __restrict__ wts,
                                             const int* __restrict__ shifts,
                                             float* __restrict__ out) {
    __shared__ float w[TOPK];
    __shared__ int   sh[TOPK];
    const int id = blockIdx.x;
    const int b = id & 7;                // XCD affinity
    const int l = id >> 3;
    const int t = threadIdx.x;
    if (t < TOPK) { w[t] = wts[b * TOPK + t]; sh[t] = shifts[t]; }
    __syncthreads();
    float4 acc = make_float4(0.f, 0.f, 0.f, 0.f);
    const float4* vb = (const float4*)(vals + (size_t)b * NL * ND);
    #pragma unroll 4
    for (int kkk = 0; kkk < TOPK; ++kkk) {
        const int sl = (l + sh[kkk]) & (NL - 1);
        const float4 x = vb[(size_t)sl * (ND / 4) + t];
        const float wk = w[kkk];
        acc.x = fmaf(wk, x.x, acc.x);
        acc.y = fmaf(wk, x.y, acc.y);
        acc.z = fmaf(wk, x.z, acc.z);
        acc.w = fmaf(wk, x.w, acc.w);
    }
    ((float4*)out)[((size_t)b * NL + l) * (ND / 4) + t] = acc;
}

extern "C" void kernel_launch(void* const* d_in, const int* in_sizes, int n_in,
                              void* d_out, int out_size, void* d_ws, size_t ws_size,
                              hipStream_t stream) {
    const float* q = (const float*)d_in[0];
    const float* k = (const float*)d_in[1];
    const float* v = (const float*)d_in[2];
    float* out    = (float*)d_out;

    const size_t plane = (size_t)ND * NL;                 // 512*1024
    unsigned short* Thi = (unsigned short*)d_ws;          // 2*NB planes bf16
    unsigned short* Tlo = Thi + 2 * NB * plane;           // 2*NB planes bf16
    float* S      = (float*)(Tlo + 2 * NB * plane);       // NB * 1023
    float* pbar   = S + NB * 1023;                        // NB * 2*NF
    float* mv     = pbar + NB * 2 * NF;                   // NB * NT
    float* wts    = mv + NB * NT;                         // NB * TOPK
    int*   shifts = (int*)(wts + NB * TOPK);              // TOPK ints

    k_tr  <<<dim3(128, NB, 2), 256, 0, stream>>>(q, k, Thi, Tlo, S);
    k_gemm<<<1024, 256, 0, stream>>>(Thi, Tlo, S);
    k_pdft<<<dim3(NF, NB), 64, 0, stream>>>(S, pbar);
    k_mean<<<dim3(512, NB), 256, 0, stream>>>(pbar, mv);
    k_topk<<<NB, 256, 0, stream>>>(mv, wts, shifts);
    k_out <<<NL * NB, 128, 0, stream>>>(v, wts, shifts, out);
}

// Round 10
// 182.529 us; speedup vs baseline: 1.2683x; 1.1105x over previous
//
#include <hip/hip_runtime.h>
#include <math.h>

#define NB 8
#define NL 1024
#define ND 512
#define NF 513          // rfft bins of length-1024 transform
#define NT 2047         // L + S - 1
#define TOPK 20         // int(3 * log(1024))

typedef __attribute__((ext_vector_type(8))) short short8;
typedef __attribute__((ext_vector_type(4))) float f32x4;

static __device__ __forceinline__ unsigned short bf16_rne(float x) {
    unsigned int u = __builtin_bit_cast(unsigned int, x);
    unsigned int r = (u + 0x7fffu + ((u >> 16) & 1u)) >> 16;
    return (unsigned short)r;
}
static __device__ __forceinline__ float bf16_to_f(unsigned short h) {
    unsigned int u = ((unsigned int)h) << 16;
    return __builtin_bit_cast(float, u);
}

// ---------------------------------------------------------------------------
// Kernel T: transpose + split-bf16 convert; also zeroes S (replaces memset).
// q[b][l][d] f32 -> Thi/Tlo[(which*NB+b)][d][l] bf16 (hi = rne(x), lo = rne(x-hi))
// ---------------------------------------------------------------------------
__global__ __launch_bounds__(256) void k_tr(const float* __restrict__ q,
                                            const float* __restrict__ kk,
                                            unsigned short* __restrict__ Thi,
                                            unsigned short* __restrict__ Tlo,
                                            float* __restrict__ S) {
    __shared__ float tile[64][65];
    const int which = blockIdx.z;          // 0=q, 1=k
    const int b  = blockIdx.y;
    const int l0 = (blockIdx.x & 15) * 64;
    const int d0 = (blockIdx.x >> 4) * 64;
    const int t = threadIdx.x;
    if (which == 0 && blockIdx.x == 0) {   // 8 blocks zero S[b][*]
        for (int i = t; i < 1023; i += 256) S[b * 1023 + i] = 0.f;
    }
    const float* src = (which ? kk : q) + (size_t)b * NL * ND;
    const int r = t >> 4, c = t & 15;
    #pragma unroll
    for (int rr = 0; rr < 4; ++rr) {
        const float4 v = *(const float4*)&src[(size_t)(l0 + r + 16 * rr) * ND + d0 + c * 4];
        tile[r + 16 * rr][c * 4 + 0] = v.x;
        tile[r + 16 * rr][c * 4 + 1] = v.y;
        tile[r + 16 * rr][c * 4 + 2] = v.z;
        tile[r + 16 * rr][c * 4 + 3] = v.w;
    }
    __syncthreads();
    unsigned short* hi = Thi + ((size_t)which * NB + b) * (size_t)ND * NL;
    unsigned short* lo = Tlo + ((size_t)which * NB + b) * (size_t)ND * NL;
    #pragma unroll
    for (int p = 0; p < 2; ++p) {
        const int c2 = t + 256 * p;        // 0..511
        const int dl = c2 >> 3;            // 0..63
        const int l8 = (c2 & 7) * 8;
        short8 vh, vl;
        #pragma unroll
        for (int i = 0; i < 8; ++i) {
            const float x = tile[l8 + i][dl];
            const unsigned short h = bf16_rne(x);
            vh[i] = (short)h;
            vl[i] = (short)bf16_rne(x - bf16_to_f(h));
        }
        *(short8*)&hi[(size_t)(d0 + dl) * NL + l0 + l8] = vh;
        *(short8*)&lo[(size_t)(d0 + dl) * NL + l0 + l8] = vl;
    }
}

// ---------------------------------------------------------------------------
// Kernel G: MFMA Gram GEMM.  G = qhi·khi^T + qhi·klo^T + qlo·khi^T.
// r9 post-mortem: GBK=32/KSPLIT=8 regressed (56 µs vs r6's <=40): per-block
// fixed overhead (cold loads, barriers, atomic epilogue) dominates this tiny
// GEMM, so more/smaller blocks lose. Reverted to the r6 config measured in
// the 185-µs run: GBK=64, GKT=4, KSPLIT=4, grid 512, launch_bounds(256,2),
// flat-id batch/XCD affinity, per-wave sd slices, GPAD=8.
// ---------------------------------------------------------------------------
#define GBK 64
#define GPAD 8
#define GKT 4            // K-steps per block (K = 256 per block)

__global__ __launch_bounds__(256, 2) void k_gemm(const unsigned short* __restrict__ Thi,
                                                 const unsigned short* __restrict__ Tlo,
                                                 float* __restrict__ S) {
    __shared__ unsigned short Ahi[128][GBK + GPAD];
    __shared__ unsigned short Alo[128][GBK + GPAD];
    __shared__ unsigned short Bhi[128][GBK + GPAD];
    __shared__ unsigned short Blo[128][GBK + GPAD];
    __shared__ float sd4[4][256];
    const int id   = blockIdx.x;
    const int b    = id & 7;                   // XCD affinity by batch
    const int rest = id >> 3;                  // 0..63
    const int mt = rest & 3, nt = (rest >> 2) & 3, kq = rest >> 4;  // kq 0..3
    const int tid  = threadIdx.x;
    const int lane = tid & 63, w = tid >> 6;
    const int wr = w >> 1, wc = w & 1;         // wave -> 64x64 sub-tile
    const int m = lane & 15, g = lane >> 4;    // frag row/col + k-group

    const size_t plane = (size_t)ND * NL;
    const unsigned short* qhi = Thi + (size_t)b * plane;
    const unsigned short* khi = Thi + ((size_t)NB + b) * plane;
    const unsigned short* qlo = Tlo + (size_t)b * plane;
    const unsigned short* klo = Tlo + ((size_t)NB + b) * plane;

    f32x4 acc[4][4];
    #pragma unroll
    for (int i = 0; i < 4; ++i)
        #pragma unroll
        for (int j = 0; j < 4; ++j) acc[i][j] = (f32x4)(0.f);

    const int kbase = kq * GKT;
    short8 r_ah[4], r_al[4], r_bh[4], r_bl[4];
    #pragma unroll
    for (int p = 0; p < 4; ++p) {
        const int cc  = tid + 256 * p;         // 0..1023
        const int row = cc >> 3, col8 = (cc & 7) * 8;
        const size_t ga = (size_t)(mt * 128 + row) * NL + kbase * GBK + col8;
        const size_t gb = (size_t)(nt * 128 + row) * NL + kbase * GBK + col8;
        r_ah[p] = *(const short8*)&qhi[ga];
        r_al[p] = *(const short8*)&qlo[ga];
        r_bh[p] = *(const short8*)&khi[gb];
        r_bl[p] = *(const short8*)&klo[gb];
    }

    for (int kt = 0; kt < GKT; ++kt) {
        __syncthreads();
        #pragma unroll
        for (int p = 0; p < 4; ++p) {
            const int cc  = tid + 256 * p;
            const int row = cc >> 3, col8 = (cc & 7) * 8;
            *(short8*)&Ahi[row][col8] = r_ah[p];
            *(short8*)&Alo[row][col8] = r_al[p];
            *(short8*)&Bhi[row][col8] = r_bh[p];
            *(short8*)&Blo[row][col8] = r_bl[p];
        }
        __syncthreads();
        if (kt + 1 < GKT) {                    // prefetch next K-step; lands
            #pragma unroll                     // during the MFMA phase below
            for (int p = 0; p < 4; ++p) {
                const int cc  = tid + 256 * p;
                const int row = cc >> 3, col8 = (cc & 7) * 8;
                const size_t ga = (size_t)(mt * 128 + row) * NL + (kbase + kt + 1) * GBK + col8;
                const size_t gb = (size_t)(nt * 128 + row) * NL + (kbase + kt + 1) * GBK + col8;
                r_ah[p] = *(const short8*)&qhi[ga];
                r_al[p] = *(const short8*)&qlo[ga];
                r_bh[p] = *(const short8*)&khi[gb];
                r_bl[p] = *(const short8*)&klo[gb];
            }
        }
        #pragma unroll
        for (int ks = 0; ks < 2; ++ks) {
            short8 ah[4], al[4], bh[4], bl[4];
            #pragma unroll
            for (int i = 0; i < 4; ++i) {
                ah[i] = *(const short8*)&Ahi[wr * 64 + i * 16 + m][ks * 32 + g * 8];
                al[i] = *(const short8*)&Alo[wr * 64 + i * 16 + m][ks * 32 + g * 8];
            }
            #pragma unroll
            for (int j = 0; j < 4; ++j) {
                bh[j] = *(const short8*)&Bhi[wc * 64 + j * 16 + m][ks * 32 + g * 8];
                bl[j] = *(const short8*)&Blo[wc * 64 + j * 16 + m][ks * 32 + g * 8];
            }
            #pragma unroll
            for (int i = 0; i < 4; ++i)
                #pragma unroll
                for (int j = 0; j < 4; ++j) {
                    acc[i][j] = __builtin_amdgcn_mfma_f32_16x16x32_bf16(ah[i], bh[j], acc[i][j], 0, 0, 0);
                    acc[i][j] = __builtin_amdgcn_mfma_f32_16x16x32_bf16(ah[i], bl[j], acc[i][j], 0, 0, 0);
                    acc[i][j] = __builtin_amdgcn_mfma_f32_16x16x32_bf16(al[i], bh[j], acc[i][j], 0, 0, 0);
                }
        }
    }

    // --- epilogue: diagonal sums. delta = row - col (global: + (mt-nt)*128) ---
    for (int i = tid; i < 1024; i += 256) ((float*)sd4)[i] = 0.f;
    __syncthreads();
    float bin[7][4];
    #pragma unroll
    for (int u = 0; u < 7; ++u)
        #pragma unroll
        for (int r2 = 0; r2 < 4; ++r2) bin[u][r2] = 0.f;
    #pragma unroll
    for (int i = 0; i < 4; ++i)
        #pragma unroll
        for (int j = 0; j < 4; ++j)
            #pragma unroll
            for (int r2 = 0; r2 < 4; ++r2) bin[i - j + 3][r2] += acc[i][j][r2];
    const int basei = (wr - wc) * 64 + g * 4 - m + 127;
    #pragma unroll
    for (int u = 0; u < 7; ++u)
        #pragma unroll
        for (int r2 = 0; r2 < 4; ++r2)
            atomicAdd(&sd4[w][basei + (u - 3) * 16 + r2], bin[u][r2]);
    __syncthreads();
    const int doff = (mt - nt) * 128 + 511 - 127;
    if (tid < 255) {
        const float vsum = sd4[0][tid] + sd4[1][tid] + sd4[2][tid] + sd4[3][tid];
        atomicAdd(&S[b * 1023 + doff + tid], vsum);
    }
}

// ---------------------------------------------------------------------------
// Kernel P: P̄[b][f] = sum_j S[b][j] e^{-2πi f (j-511)/1024}.
// One wave per (b,f): lanes split j, exact sincosf per term, butterfly reduce.
// ---------------------------------------------------------------------------
__global__ __launch_bounds__(64) void k_pdft(const float* __restrict__ S,
                                             float* __restrict__ pbar) {
    const int b = blockIdx.y;
    const int f = blockIdx.x;              // 0..512
    const int lane = threadIdx.x;
    const float w = 2.0f * 3.14159265358979323846f / 1024.0f;
    float re = 0.f, im = 0.f;
    #pragma unroll
    for (int i = 0; i < 16; ++i) {
        const int j = lane + 64 * i;
        if (j < 1023) {
            const int mm = (f * (j - 511)) & 1023;   // exact mod (pow2, two's compl.)
            float s, c;
            sincosf(w * (float)mm, &s, &c);
            const float x = S[b * 1023 + j];
            re = fmaf(x, c, re);
            im = fmaf(x, -s, im);
        }
    }
    #pragma unroll
    for (int off = 32; off; off >>= 1) {
        re += __shfl_xor(re, off);
        im += __shfl_xor(im, off);
    }
    if (lane == 0) {
        pbar[b * 2 * NF + 2 * f]     = re;
        pbar[b * 2 * NF + 2 * f + 1] = im;
    }
}

// ---------------------------------------------------------------------------
// Kernel B: mean_value[b,t] = (1/(2047*1024)) * (P̄[0] + 2Σ_{f=1..512}
//            (P̄re[f] cos(2πft/2047) - P̄im[f] sin(2πft/2047)))
// One wave per (b,t), 4 waves/block; lanes split f, butterfly reduce.
// ---------------------------------------------------------------------------
__global__ __launch_bounds__(256) void k_mean(const float* __restrict__ pbar,
                                              float* __restrict__ mv) {
    __shared__ float P[2 * NF];
    const int b = blockIdx.y;
    for (int i = threadIdx.x; i < 2 * NF; i += 256)
        P[i] = pbar[(size_t)b * (2 * NF) + i];
    __syncthreads();
    const int wave = threadIdx.x >> 6, lane = threadIdx.x & 63;
    const int t = blockIdx.x * 4 + wave;   // 0..2047
    if (t >= NT) return;
    const float w2 = 2.0f * 3.14159265358979323846f / 2047.0f;
    float acc = 0.f;
    #pragma unroll
    for (int i = 0; i < 8; ++i) {
        const int f = 1 + lane + 64 * i;   // covers 1..512 exactly
        const int mm = (f * t) % 2047;
        float s, c;
        sincosf(w2 * (float)mm, &s, &c);
        acc = fmaf(P[2 * f], c, acc);
        acc = fmaf(-P[2 * f + 1], s, acc);
    }
    acc *= 2.0f;
    #pragma unroll
    for (int off = 32; off; off >>= 1) acc += __shfl_xor(acc, off);
    if (lane == 0)
        mv[(size_t)b * NT + t] = (acc + P[0]) * (1.0f / (2047.0f * 1024.0f));
}

// ---------------------------------------------------------------------------
// Kernel C: per-batch exact top-20 (ties -> lower index), softmax; batch 0's
// indices -> shifts. 256 threads: 8-iter scans + wave/LDS reduce.
// ---------------------------------------------------------------------------
__global__ __launch_bounds__(256) void k_topk(const float* __restrict__ mv,
                                              float* __restrict__ wts,
                                              int* __restrict__ shifts) {
    __shared__ float v[NT];
    __shared__ float topv[TOPK];
    __shared__ int   topi[TOPK];
    __shared__ float wv[4];
    __shared__ int   wi[4];
    const int b = blockIdx.x;
    const int t = threadIdx.x;
    const int lane = t & 63, wave = t >> 6;
    for (int i = t; i < NT; i += 256) v[i] = mv[(size_t)b * NT + i];
    __syncthreads();
    for (int kkk = 0; kkk < TOPK; ++kkk) {
        float bv = -INFINITY; int bi = 0x7fffffff;
        #pragma unroll
        for (int s = 0; s < 8; ++s) {
            const int i = t + 256 * s;
            if (i < NT) {
                const float x = v[i];
                if (x > bv) { bv = x; bi = i; }
            }
        }
        #pragma unroll
        for (int off = 32; off; off >>= 1) {
            const float ov = __shfl_down(bv, off);
            const int   oi = __shfl_down(bi, off);
            if (ov > bv || (ov == bv && oi < bi)) { bv = ov; bi = oi; }
        }
        if (lane == 0) { wv[wave] = bv; wi[wave] = bi; }
        __syncthreads();
        if (t == 0) {
            bv = wv[0]; bi = wi[0];
            #pragma unroll
            for (int ww = 1; ww < 4; ++ww)
                if (wv[ww] > bv || (wv[ww] == bv && wi[ww] < bi)) { bv = wv[ww]; bi = wi[ww]; }
            topv[kkk] = bv; topi[kkk] = bi;
            v[bi] = -INFINITY;
        }
        __syncthreads();
    }
    if (t == 0) {
        float m = topv[0], sum = 0.f, e[TOPK];
        #pragma unroll
        for (int i = 0; i < TOPK; ++i) { e[i] = expf(topv[i] - m); sum += e[i]; }
        #pragma unroll
        for (int i = 0; i < TOPK; ++i) wts[b * TOPK + i] = e[i] / sum;
        if (b == 0) {
            #pragma unroll
            for (int i = 0; i < TOPK; ++i) shifts[i] = topi[i];
        }
    }
}

// ---------------------------------------------------------------------------
// Kernel D: out[b,l,:] = Σ_k w[b,k] * values[b, (l+shift_k) & 1023, :]
// b = blockIdx.x & 7: XCD affinity so values[b] (2.1 MB) stays L2-resident.
// ---------------------------------------------------------------------------
__global__ __launch_bounds__(128) void k_out(const float* __restrict__ vals,
                                             const float* __restrict__ wts,
                                             const int* __restrict__ shifts,
                                             float* __restrict__ out) {
    __shared__ float w[TOPK];
    __shared__ int   sh[TOPK];
    const int id = blockIdx.x;
    const int b = id & 7;                // XCD affinity
    const int l = id >> 3;
    const int t = threadIdx.x;
    if (t < TOPK) { w[t] = wts[b * TOPK + t]; sh[t] = shifts[t]; }
    __syncthreads();
    float4 acc = make_float4(0.f, 0.f, 0.f, 0.f);
    const float4* vb = (const float4*)(vals + (size_t)b * NL * ND);
    #pragma unroll 4
    for (int kkk = 0; kkk < TOPK; ++kkk) {
        const int sl = (l + sh[kkk]) & (NL - 1);
        const float4 x = vb[(size_t)sl * (ND / 4) + t];
        const float wk = w[kkk];
        acc.x = fmaf(wk, x.x, acc.x);
        acc.y = fmaf(wk, x.y, acc.y);
        acc.z = fmaf(wk, x.z, acc.z);
        acc.w = fmaf(wk, x.w, acc.w);
    }
    ((float4*)out)[((size_t)b * NL + l) * (ND / 4) + t] = acc;
}

extern "C" void kernel_launch(void* const* d_in, const int* in_sizes, int n_in,
                              void* d_out, int out_size, void* d_ws, size_t ws_size,
                              hipStream_t stream) {
    const float* q = (const float*)d_in[0];
    const float* k = (const float*)d_in[1];
    const float* v = (const float*)d_in[2];
    float* out    = (float*)d_out;

    const size_t plane = (size_t)ND * NL;                 // 512*1024
    unsigned short* Thi = (unsigned short*)d_ws;          // 2*NB planes bf16
    unsigned short* Tlo = Thi + 2 * NB * plane;           // 2*NB planes bf16
    float* S      = (float*)(Tlo + 2 * NB * plane);       // NB * 1023
    float* pbar   = S + NB * 1023;                        // NB * 2*NF
    float* mv     = pbar + NB * 2 * NF;                   // NB * NT
    float* wts    = mv + NB * NT;                         // NB * TOPK
    int*   shifts = (int*)(wts + NB * TOPK);              // TOPK ints

    k_tr  <<<dim3(128, NB, 2), 256, 0, stream>>>(q, k, Thi, Tlo, S);
    k_gemm<<<512, 256, 0, stream>>>(Thi, Tlo, S);
    k_pdft<<<dim3(NF, NB), 64, 0, stream>>>(S, pbar);
    k_mean<<<dim3(512, NB), 256, 0, stream>>>(pbar, mv);
    k_topk<<<NB, 256, 0, stream>>>(mv, wts, shifts);
    k_out <<<NL * NB, 128, 0, stream>>>(v, wts, shifts, out);
}